// Round 2
// baseline (236.417 us; speedup 1.0000x reference)
//
#include <hip/hip_runtime.h>
#include <hip/hip_bf16.h>
#include <stdint.h>

// Problem constants (fixed by reference)
#define B_  4
#define N_  8192
#define M_  8192
#define D_  64
#define NT_ 64   // N_/128
#define MT_ 64   // M_/128

typedef __attribute__((ext_vector_type(8))) short bhalf8;   // 8 bf16 = 4 VGPRs (MFMA A/B frag)
typedef __attribute__((ext_vector_type(4))) float f32x4;    // MFMA C/D frag

// ---- workspace layout (bytes) ----
static const size_t OFF_A   = 0;
static const size_t OFF_B   = (size_t)B_ * N_ * D_ * 2;                 // 4,194,304
static const size_t OFF_NF  = OFF_B + (size_t)B_ * M_ * D_ * 2;         // 8,388,608
static const size_t OFF_NF2 = OFF_NF + (size_t)B_ * N_ * 4;             // 8,519,680
static const size_t OFF_RP  = OFF_NF2 + (size_t)B_ * M_ * 4;            // 8,650,752
static const size_t OFF_CP  = OFF_RP + (size_t)B_ * NT_ * MT_ * 128 * 4;// 17,039,360
static const size_t OFF_SM  = OFF_CP + (size_t)B_ * MT_ * NT_ * 128 * 4;// 25,427,968

// ---------------- prep: bf16 convert + fp32 norms (one wave per point) ----------------
__global__ void chamfer_prep(const float* __restrict__ f, const float* __restrict__ f2,
                             __hip_bfloat16* __restrict__ A, __hip_bfloat16* __restrict__ Bb,
                             float* __restrict__ nf, float* __restrict__ nf2) {
    int wid  = (blockIdx.x * blockDim.x + threadIdx.x) >> 6;  // global wave id = point id
    int lane = threadIdx.x & 63;
    const float* src; __hip_bfloat16* dst; float* nrm; float scale; int p;
    if (wid < B_ * N_) { src = f;  dst = A;  nrm = nf;  scale = -2.0f; p = wid; }
    else               { src = f2; dst = Bb; nrm = nf2; scale =  1.0f; p = wid - B_ * N_; }
    float v = src[(size_t)p * D_ + lane];
    dst[(size_t)p * D_ + lane] = __float2bfloat16(v * scale);  // -2x is exact in bf16
    float s = v * v;
    #pragma unroll
    for (int m = 1; m < 64; m <<= 1) s += __shfl_xor(s, m, 64);
    if (lane == 0) nrm[p] = s;
}

// ---------------- main tile kernel: 128x128 per block, 2x2 waves of 64x64 ----------------
__global__ __launch_bounds__(256) void chamfer_tile(
        const __hip_bfloat16* __restrict__ A, const __hip_bfloat16* __restrict__ Bb,
        const float* __restrict__ nf, const float* __restrict__ nf2,
        float* __restrict__ rowpart, float* __restrict__ colpart) {
    const int b  = blockIdx.z;
    const int nt = blockIdx.y, mt = blockIdx.x;
    const int tid = threadIdx.x;
    const int wave = tid >> 6, lane = tid & 63;
    const int wr = wave >> 1, wc = wave & 1;
    const int q = lane >> 4, c = lane & 15;
    const int n0 = nt * 128 + wr * 64;
    const int m0 = mt * 128 + wc * 64;

    const __hip_bfloat16* Ap = A  + ((size_t)b * N_ + n0) * D_;
    const __hip_bfloat16* Bp = Bb + ((size_t)b * M_ + m0) * D_;

    // A frag: A[m=lane&15][k=q*8+j] (m89/m120-verified layout); same pattern for B (B^T GEMM).
    bhalf8 af[4][2], bf[4][2];
    #pragma unroll
    for (int i = 0; i < 4; i++) {
        #pragma unroll
        for (int ks = 0; ks < 2; ks++) {
            af[i][ks] = *(const bhalf8*)(Ap + (size_t)(i * 16 + c) * D_ + ks * 32 + q * 8);
            bf[i][ks] = *(const bhalf8*)(Bp + (size_t)(i * 16 + c) * D_ + ks * 32 + q * 8);
        }
    }

    f32x4 acc[4][4];
    #pragma unroll
    for (int i = 0; i < 4; i++)
        #pragma unroll
        for (int j = 0; j < 4; j++)
            acc[i][j] = (f32x4){0.f, 0.f, 0.f, 0.f};

    #pragma unroll
    for (int ks = 0; ks < 2; ks++)
        #pragma unroll
        for (int i = 0; i < 4; i++)
            #pragma unroll
            for (int j = 0; j < 4; j++)
                acc[i][j] = __builtin_amdgcn_mfma_f32_16x16x32_bf16(af[i][ks], bf[j][ks], acc[i][j], 0, 0, 0);
    // acc[i][j][r] = -2 * dot(f[n0+i*16+q*4+r], f_[m0+j*16+c])   (C/D: col=lane&15, row=q*4+reg)

    // norms
    float nfr[16];
    #pragma unroll
    for (int i = 0; i < 4; i++)
        #pragma unroll
        for (int r = 0; r < 4; r++)
            nfr[i * 4 + r] = nf[(size_t)b * N_ + n0 + i * 16 + q * 4 + r];
    float nfc[4];
    #pragma unroll
    for (int j = 0; j < 4; j++)
        nfc[j] = nf2[(size_t)b * M_ + m0 + j * 16 + c];

    // LDS combine buffers.
    // rowbuf: [column-owner 0..31 = wc*16+c][BLOCK row 0..127 = wr*64 + i*16 + q*4 + r]
    //   (R0 bug: second index omitted wr*64 -> wr=0/1 waves raced on the same slots)
    // colbuf: [row-owner 0..7 = wr*4+q][block col 0..127 = wc*64 + j*16 + c]
    __shared__ __align__(16) float rowbuf[32][132];  // 132 pad: 528B rows, 16B-aligned
    __shared__ __align__(16) float colbuf[8][132];

    // row partials: per (i,r) min over this lane's 4 columns (j-tiles) of (acc + nf_[col])
    #pragma unroll
    for (int i = 0; i < 4; i++) {
        f32x4 rv;
        #pragma unroll
        for (int r = 0; r < 4; r++) {
            float v = acc[i][0][r] + nfc[0];
            #pragma unroll
            for (int j = 1; j < 4; j++) v = fminf(v, acc[i][j][r] + nfc[j]);
            rv[r] = v;
        }
        *(f32x4*)&rowbuf[wc * 16 + c][wr * 64 + i * 16 + q * 4] = rv;
    }
    // col partials: per j min over this lane's 16 rows (i,r) of (acc + nf[row])
    #pragma unroll
    for (int j = 0; j < 4; j++) {
        float v = 3.0e38f;
        #pragma unroll
        for (int i = 0; i < 4; i++)
            #pragma unroll
            for (int r = 0; r < 4; r++)
                v = fminf(v, acc[i][j][r] + nfr[i * 4 + r]);
        colbuf[wr * 4 + q][wc * 64 + j * 16 + c] = v;
    }
    __syncthreads();

    if (tid < 128) {
        float v = rowbuf[0][tid];
        #pragma unroll 8
        for (int cc = 1; cc < 32; cc++) v = fminf(v, rowbuf[cc][tid]);
        rowpart[(((size_t)b * NT_ + nt) * MT_ + mt) * 128 + tid] = v;
    } else {
        int t = tid - 128;
        float v = colbuf[0][t];
        #pragma unroll
        for (int qq = 1; qq < 8; qq++) v = fminf(v, colbuf[qq][t]);
        colpart[(((size_t)b * MT_ + mt) * NT_ + nt) * 128 + t] = v;
    }
}

// ---------------- reduce: min over tile-partials + norm, then block sum ----------------
__global__ void chamfer_reduce(const float* __restrict__ rowpart, const float* __restrict__ colpart,
                               const float* __restrict__ nf, const float* __restrict__ nf2,
                               float* __restrict__ sums) {
    int blk = blockIdx.x;            // 0..255 : 0-127 rows (f2f_), 128-255 cols (f_2f)
    int tid = threadIdx.x;
    bool isrow = blk < 128;
    int gid = (isrow ? blk : blk - 128) * 256 + tid;   // 0..32767 point id
    int b = gid >> 13;               // /8192
    int n = gid & 8191;
    int t = n >> 7, r = n & 127;
    const float* part = isrow ? rowpart : colpart;
    size_t base = ((size_t)b * 64 + t) * 64;
    float v = part[(base + 0) * 128 + r];
    #pragma unroll 8
    for (int u = 1; u < 64; u++) v = fminf(v, part[(base + u) * 128 + r]);
    v += (isrow ? nf : nf2)[gid];    // add the norm that was factored out of the min

    __shared__ float sbuf[256];
    sbuf[tid] = v;
    __syncthreads();
    for (int s = 128; s > 0; s >>= 1) {
        if (tid < s) sbuf[tid] += sbuf[tid + s];
        __syncthreads();
    }
    if (tid == 0) sums[blk] = sbuf[0];
}

__global__ void chamfer_final(const float* __restrict__ sums, float* __restrict__ out) {
    int tid = threadIdx.x;  // 256 threads
    __shared__ float sbuf[256];
    float v = sums[tid];
    v *= (tid < 128) ? (1.0f / ((float)B_ * (float)N_)) : (1.0f / ((float)B_ * (float)M_));
    sbuf[tid] = v;
    __syncthreads();
    for (int s = 128; s > 0; s >>= 1) {
        if (tid < s) sbuf[tid] += sbuf[tid + s];
        __syncthreads();
    }
    if (tid == 0) out[0] = sbuf[0];
}

extern "C" void kernel_launch(void* const* d_in, const int* in_sizes, int n_in,
                              void* d_out, int out_size, void* d_ws, size_t ws_size,
                              hipStream_t stream) {
    const float* f  = (const float*)d_in[0];
    const float* f2 = (const float*)d_in[1];
    char* ws = (char*)d_ws;
    __hip_bfloat16* A   = (__hip_bfloat16*)(ws + OFF_A);
    __hip_bfloat16* Bb  = (__hip_bfloat16*)(ws + OFF_B);
    float* nf      = (float*)(ws + OFF_NF);
    float* nf2     = (float*)(ws + OFF_NF2);
    float* rowpart = (float*)(ws + OFF_RP);
    float* colpart = (float*)(ws + OFF_CP);
    float* sums    = (float*)(ws + OFF_SM);
    float* out     = (float*)d_out;

    // prep: one wave per point, 4 points per 256-thread block
    int nwaves = B_ * N_ + B_ * M_;                     // 65536
    chamfer_prep<<<dim3(nwaves / 4), dim3(256), 0, stream>>>(f, f2, A, Bb, nf, nf2);

    // main: 128x128 tiles
    chamfer_tile<<<dim3(MT_, NT_, B_), dim3(256), 0, stream>>>(A, Bb, nf, nf2, rowpart, colpart);

    // reduce partial mins -> block sums -> scalar
    chamfer_reduce<<<dim3(256), dim3(256), 0, stream>>>(rowpart, colpart, nf, nf2, sums);
    chamfer_final<<<dim3(1), dim3(256), 0, stream>>>(sums, out);
}

// Round 3
// 218.917 us; speedup vs baseline: 1.0799x; 1.0799x over previous
//
#include <hip/hip_runtime.h>
#include <hip/hip_bf16.h>
#include <stdint.h>

// Problem constants (fixed by reference)
#define B_  4
#define N_  8192
#define M_  8192
#define D_  64
#define NT_ 64   // N_/128
#define MT_ 64   // M_/128
#define RBN ((B_ * N_) / 16)   // 2048 16-row blocks, A side (all batches)
#define RBM ((B_ * M_) / 16)   // 2048, B side

typedef __attribute__((ext_vector_type(8))) short bhalf8;   // 8 bf16 = 4 VGPRs (MFMA A/B frag)
typedef __attribute__((ext_vector_type(4))) float f32x4;

// ---- workspace layout (bytes) ----
// Aperm/Bperm: bf16 in MFMA-fragment-ready chunk order:
//   chunk(rb_loc, ks, q, c) = X[rb_loc*16 + c][ks*32 + q*8 .. +7]  (rb_loc includes batch: b*512+rb)
//   stored at chunk index (rb_loc*2 + ks)*64 + (q*16 + c)  -> a fragment load is lane-contiguous 1KB.
static const size_t OFF_A   = 0;
static const size_t OFF_B   = OFF_A + (size_t)B_ * N_ * D_ * 2;          // 4 MB
static const size_t OFF_NF  = OFF_B + (size_t)B_ * M_ * D_ * 2;          // 8 MB
static const size_t OFF_NF2 = OFF_NF + (size_t)B_ * N_ * 4;
static const size_t OFF_RP  = OFF_NF2 + (size_t)B_ * M_ * 4;
static const size_t OFF_CP  = OFF_RP + (size_t)B_ * NT_ * MT_ * 128 * 4;
static const size_t OFF_SM  = OFF_CP + (size_t)B_ * MT_ * NT_ * 128 * 4; // 512 floats

// ---------------- prep: fragment-ready bf16 layout + fp32 norms ----------------
// wave w: rb_glob = w>>1 (0..4095: A side then B side), ks = w&1; lane = q*16+c.
// Each lane: 8 floats of row (rb*16+c), k range ks*32+q*8..+7 -> one 16B chunk store, lane-contiguous.
__global__ __launch_bounds__(256) void chamfer_prep(
        const float* __restrict__ f, const float* __restrict__ f2,
        unsigned short* __restrict__ Ap, unsigned short* __restrict__ Bp,
        float* __restrict__ nf, float* __restrict__ nf2) {
    const int tid = threadIdx.x;
    const int bw = tid >> 6, lane = tid & 63;
    const int w = blockIdx.x * 4 + bw;
    const int rb_glob = w >> 1, ks = w & 1;
    const int q = lane >> 4, c = lane & 15;
    const bool isA = rb_glob < RBN;
    const int rb_loc = isA ? rb_glob : rb_glob - RBN;
    const float* src = isA ? f : f2;
    unsigned short* dst = isA ? Ap : Bp;
    const float scale = isA ? -2.0f : 1.0f;   // fold the -2 into A; exact in bf16

    const float* s0 = src + ((size_t)rb_loc * 16 + c) * 64 + ks * 32 + q * 8;
    f32x4 v0 = *(const f32x4*)s0;
    f32x4 v1 = *(const f32x4*)(s0 + 4);

    bhalf8 o;
    float ss = 0.f;
    #pragma unroll
    for (int j = 0; j < 4; j++) {
        ss += v0[j] * v0[j];
        union { __hip_bfloat16 h; unsigned short u; } cv;
        cv.h = __float2bfloat16(v0[j] * scale);
        o[j] = (short)cv.u;
    }
    #pragma unroll
    for (int j = 0; j < 4; j++) {
        ss += v1[j] * v1[j];
        union { __hip_bfloat16 h; unsigned short u; } cv;
        cv.h = __float2bfloat16(v1[j] * scale);
        o[4 + j] = (short)cv.u;
    }
    *(bhalf8*)(dst + ((size_t)(rb_loc * 2 + ks) * 64 + lane) * 8) = o;  // coalesced 1KB/wave

    // norm: sum of raw v^2 over the row. Reduce over q (lane bits 4,5), then over ks via LDS.
    ss += __shfl_xor(ss, 16, 64);
    ss += __shfl_xor(ss, 32, 64);
    __shared__ float nb[4][16];
    if (q == 0) nb[bw][c] = ss;
    __syncthreads();
    if (tid < 32) {
        int rbslot = tid >> 4, cc = tid & 15;
        int rbg = blockIdx.x * 2 + rbslot;          // waves (2*rbslot, 2*rbslot+1) = its two ks halves
        float tot = nb[rbslot * 2][cc] + nb[rbslot * 2 + 1][cc];
        bool iA = rbg < RBN;
        int rl = iA ? rbg : rbg - RBN;
        (iA ? nf : nf2)[(size_t)rl * 16 + cc] = tot;
    }
}

// ---------------- main tile kernel: 128x128 per block, direct coalesced frag loads ----------------
__global__ __launch_bounds__(256) void chamfer_tile(
        const unsigned short* __restrict__ Ap, const unsigned short* __restrict__ Bp,
        const float* __restrict__ nf, const float* __restrict__ nf2,
        float* __restrict__ rowpart, float* __restrict__ colpart) {
    const int b  = blockIdx.z;
    const int nt = blockIdx.y, mt = blockIdx.x;
    const int tid = threadIdx.x;
    const int wave = tid >> 6, lane = tid & 63;
    const int wr = wave >> 1, wc = wave & 1;
    const int q = lane >> 4, c = lane & 15;
    const int n0 = nt * 128 + wr * 64;
    const int m0 = mt * 128 + wc * 64;
    const int rbA0 = b * 512 + nt * 8 + wr * 4;   // 16-row-block index base (includes batch)
    const int rbB0 = b * 512 + mt * 8 + wc * 4;

    // Fragment loads: lane-contiguous 16B from the permuted layout -> 1KB coalesced per instr.
    bhalf8 af[4][2], bf[4][2];
    #pragma unroll
    for (int i = 0; i < 4; i++)
        #pragma unroll
        for (int ks = 0; ks < 2; ks++) {
            af[i][ks] = *(const bhalf8*)(Ap + ((size_t)((rbA0 + i) * 2 + ks) * 64 + lane) * 8);
            bf[i][ks] = *(const bhalf8*)(Bp + ((size_t)((rbB0 + i) * 2 + ks) * 64 + lane) * 8);
        }

    f32x4 acc[4][4];
    #pragma unroll
    for (int i = 0; i < 4; i++)
        #pragma unroll
        for (int j = 0; j < 4; j++)
            acc[i][j] = (f32x4){0.f, 0.f, 0.f, 0.f};

    #pragma unroll
    for (int ks = 0; ks < 2; ks++)
        #pragma unroll
        for (int i = 0; i < 4; i++)
            #pragma unroll
            for (int j = 0; j < 4; j++)
                acc[i][j] = __builtin_amdgcn_mfma_f32_16x16x32_bf16(af[i][ks], bf[j][ks], acc[i][j], 0, 0, 0);
    // acc[i][j][r] = -2 * dot(f[n0+i*16+q*4+r], f_[m0+j*16+c])

    float nfr[16];
    #pragma unroll
    for (int i = 0; i < 4; i++)
        #pragma unroll
        for (int r = 0; r < 4; r++)
            nfr[i * 4 + r] = nf[(size_t)b * N_ + n0 + i * 16 + q * 4 + r];
    float nfc[4];
    #pragma unroll
    for (int j = 0; j < 4; j++)
        nfc[j] = nf2[(size_t)b * M_ + m0 + j * 16 + c];

    // rowbuf: [column-owner 0..31 = wc*16+c][block row 0..127 = wr*64+i*16+q*4+r]
    // colbuf: [row-owner 0..7 = wr*4+q][block col 0..127 = wc*64+j*16+c]
    __shared__ __align__(16) float rowbuf[32][132];
    __shared__ __align__(16) float colbuf[8][132];

    #pragma unroll
    for (int i = 0; i < 4; i++) {
        f32x4 rv;
        #pragma unroll
        for (int r = 0; r < 4; r++) {
            float v = acc[i][0][r] + nfc[0];
            #pragma unroll
            for (int j = 1; j < 4; j++) v = fminf(v, acc[i][j][r] + nfc[j]);
            rv[r] = v;
        }
        *(f32x4*)&rowbuf[wc * 16 + c][wr * 64 + i * 16 + q * 4] = rv;
    }
    #pragma unroll
    for (int j = 0; j < 4; j++) {
        float v = 3.0e38f;
        #pragma unroll
        for (int i = 0; i < 4; i++)
            #pragma unroll
            for (int r = 0; r < 4; r++)
                v = fminf(v, acc[i][j][r] + nfr[i * 4 + r]);
        colbuf[wr * 4 + q][wc * 64 + j * 16 + c] = v;
    }
    __syncthreads();

    if (tid < 128) {
        float v = rowbuf[0][tid];
        #pragma unroll 8
        for (int cc = 1; cc < 32; cc++) v = fminf(v, rowbuf[cc][tid]);
        rowpart[(((size_t)b * NT_ + nt) * MT_ + mt) * 128 + tid] = v;
    } else {
        int t = tid - 128;
        float v = colbuf[0][t];
        #pragma unroll
        for (int qq = 1; qq < 8; qq++) v = fminf(v, colbuf[qq][t]);
        colpart[(((size_t)b * MT_ + mt) * NT_ + nt) * 128 + t] = v;
    }
}

// ---------------- reduce: per (b, panel) block; float4 loads; one partial sum per block ----------------
__global__ __launch_bounds__(256) void chamfer_reduce(
        const float* __restrict__ rowpart, const float* __restrict__ colpart,
        const float* __restrict__ nf, const float* __restrict__ nf2,
        float* __restrict__ sums) {
    const int blk = blockIdx.x;            // 0..255 row side (b,nt); 256..511 col side (b,mt)
    const int tid = threadIdx.x;
    const bool isrow = blk < 256;
    const int loc = isrow ? blk : blk - 256;
    const int b = loc >> 6, t = loc & 63;
    const float* part = (isrow ? rowpart : colpart) + (size_t)(b * 64 + t) * 64 * 128;
    const int g = tid >> 5, s = tid & 31;

    f32x4 m = {3.0e38f, 3.0e38f, 3.0e38f, 3.0e38f};
    #pragma unroll
    for (int it = 0; it < 8; it++) {
        f32x4 v = *(const f32x4*)(part + (size_t)(it * 8 + g) * 128 + s * 4);
        m[0] = fminf(m[0], v[0]); m[1] = fminf(m[1], v[1]);
        m[2] = fminf(m[2], v[2]); m[3] = fminf(m[3], v[3]);
    }
    __shared__ __align__(16) f32x4 buf[8][32];
    buf[g][s] = m;
    __syncthreads();
    if (tid < 32) {
        f32x4 mn = buf[0][tid];
        #pragma unroll
        for (int g2 = 1; g2 < 8; g2++) {
            f32x4 v = buf[g2][tid];
            mn[0] = fminf(mn[0], v[0]); mn[1] = fminf(mn[1], v[1]);
            mn[2] = fminf(mn[2], v[2]); mn[3] = fminf(mn[3], v[3]);
        }
        f32x4 nv = *(const f32x4*)((isrow ? nf : nf2) + (size_t)b * 8192 + t * 128 + tid * 4);
        float p = (mn[0] + nv[0]) + (mn[1] + nv[1]) + (mn[2] + nv[2]) + (mn[3] + nv[3]);
        #pragma unroll
        for (int mk = 1; mk < 32; mk <<= 1) p += __shfl_xor(p, mk, 64);
        if (tid == 0) sums[blk] = p;
    }
}

__global__ void chamfer_final(const float* __restrict__ sums, float* __restrict__ out) {
    int tid = threadIdx.x;  // 256 threads
    float v = sums[tid] * (1.0f / ((float)B_ * (float)N_))
            + sums[256 + tid] * (1.0f / ((float)B_ * (float)M_));
    __shared__ float sb[256];
    sb[tid] = v;
    __syncthreads();
    for (int s = 128; s > 0; s >>= 1) {
        if (tid < s) sb[tid] += sb[tid + s];
        __syncthreads();
    }
    if (tid == 0) out[0] = sb[0];
}

extern "C" void kernel_launch(void* const* d_in, const int* in_sizes, int n_in,
                              void* d_out, int out_size, void* d_ws, size_t ws_size,
                              hipStream_t stream) {
    const float* f  = (const float*)d_in[0];
    const float* f2 = (const float*)d_in[1];
    char* ws = (char*)d_ws;
    unsigned short* Ap = (unsigned short*)(ws + OFF_A);
    unsigned short* Bp = (unsigned short*)(ws + OFF_B);
    float* nf      = (float*)(ws + OFF_NF);
    float* nf2     = (float*)(ws + OFF_NF2);
    float* rowpart = (float*)(ws + OFF_RP);
    float* colpart = (float*)(ws + OFF_CP);
    float* sums    = (float*)(ws + OFF_SM);
    float* out     = (float*)d_out;

    // prep: 2*(RBN+RBM) waves = 8192 -> 2048 blocks of 256
    chamfer_prep<<<dim3(2048), dim3(256), 0, stream>>>(f, f2, Ap, Bp, nf, nf2);

    // main: 128x128 tiles, fragments loaded coalesced from permuted layout
    chamfer_tile<<<dim3(MT_, NT_, B_), dim3(256), 0, stream>>>(Ap, Bp, nf, nf2, rowpart, colpart);

    // reduce partial mins -> 512 block sums -> scalar
    chamfer_reduce<<<dim3(512), dim3(256), 0, stream>>>(rowpart, colpart, nf, nf2, sums);
    chamfer_final<<<dim3(1), dim3(256), 0, stream>>>(sums, out);
}

// Round 4
// 133.051 us; speedup vs baseline: 1.7769x; 1.6454x over previous
//
#include <hip/hip_runtime.h>
#include <hip/hip_bf16.h>
#include <stdint.h>

// Problem constants (fixed by reference)
#define B_  4
#define N_  8192
#define M_  8192
#define D_  64
#define KP  96    // padded K: 64 data + (norm_hi, norm_lo, 1, 1) + 28 zeros
#define NT_ 64    // N_/128
#define MT_ 64    // M_/128
#define RBN ((B_ * N_) / 16)   // 2048 16-row blocks on A side
#define RBT ((B_ * (N_ + M_)) / 16)  // 4096 total

typedef __attribute__((ext_vector_type(8))) short bhalf8;   // 8 bf16 (MFMA A/B frag)
typedef __attribute__((ext_vector_type(4))) float f32x4;    // MFMA C/D frag

// ---- workspace layout (bytes) ----
// A'/B': bf16, fragment-chunk order: chunk(rb, ks=0..2, lane=q*16+c) = row (rb*16+c),
//        k = ks*32 + q*8 .. +7; stored at ((rb*3+ks)*64 + lane)*8 elems -> lane-contiguous 1KB loads.
// K extension fuses norms: A' row n = (-2f[n], nh, nl, 1, 1, 0...), B' row m = (f_[m], 1, 1, nh2, nl2, 0...)
//   => A'.B' = -2 f.f_ + ||f||^2 + ||f_||^2 = squared distance, computed entirely by MFMA.
static const size_t OFF_A  = 0;
static const size_t OFF_B  = (size_t)B_ * N_ * KP * 2;                  // 6,291,456
static const size_t OFF_RP = OFF_B + (size_t)B_ * M_ * KP * 2;          // 12,582,912
static const size_t OFF_CP = OFF_RP + (size_t)B_ * NT_ * 4 * 128 * 4;   // 13,107,200
static const size_t OFF_SM = OFF_CP + (size_t)B_ * MT_ * NT_ * 128 * 4; // 21,495,808

__device__ __forceinline__ short bf16bits(float x) {
    union { __hip_bfloat16 h; unsigned short u; } cv;
    cv.h = __float2bfloat16(x);
    return (short)cv.u;
}

// ---------------- prep: build K=96 fused-norm fragment layout ----------------
// One wave per 16-row block (4096 waves). Lane (q,c): reads 16 floats of row c,
// emits 3 chunk stores (coalesced 1KB each). Norm via in-lane squares + shfl over q.
__global__ __launch_bounds__(256) void chamfer_prep(
        const float* __restrict__ f, const float* __restrict__ f2,
        unsigned short* __restrict__ Ap, unsigned short* __restrict__ Bp) {
    const int tid = threadIdx.x;
    const int w = blockIdx.x * 4 + (tid >> 6);   // 16-row block id, 0..4095
    const int lane = tid & 63;
    const int q = lane >> 4, c = lane & 15;
    const bool isA = w < RBN;
    const int rb = isA ? w : w - RBN;
    const float* src = isA ? f : f2;
    unsigned short* dst = isA ? Ap : Bp;
    const float scale = isA ? -2.0f : 1.0f;      // fold the -2 into A; exact in bf16

    const float* row = src + ((size_t)rb * 16 + c) * 64;
    f32x4 u0 = *(const f32x4*)(row + q * 8);
    f32x4 u1 = *(const f32x4*)(row + q * 8 + 4);
    f32x4 u2 = *(const f32x4*)(row + 32 + q * 8);
    f32x4 u3 = *(const f32x4*)(row + 32 + q * 8 + 4);

    float ss = 0.f;
    #pragma unroll
    for (int k = 0; k < 4; k++)
        ss += u0[k] * u0[k] + u1[k] * u1[k] + u2[k] * u2[k] + u3[k] * u3[k];
    ss += __shfl_xor(ss, 16, 64);
    ss += __shfl_xor(ss, 32, 64);                // full ||row c||^2 in every lane

    bhalf8 o0, o1;
    #pragma unroll
    for (int k = 0; k < 4; k++) {
        o0[k]     = bf16bits(u0[k] * scale);
        o0[4 + k] = bf16bits(u1[k] * scale);
        o1[k]     = bf16bits(u2[k] * scale);
        o1[4 + k] = bf16bits(u3[k] * scale);
    }
    bhalf8 o2 = {0, 0, 0, 0, 0, 0, 0, 0};        // k=64..95 zeros except q==0 lanes
    if (q == 0) {
        float nh = __bfloat162float(__float2bfloat16(ss));  // hi part, exactly bf16
        float nl = ss - nh;                                  // residual, bf16-rounded below
        const short one = 0x3F80;                            // bf16 1.0
        if (isA) { o2[0] = bf16bits(nh); o2[1] = bf16bits(nl); o2[2] = one; o2[3] = one; }
        else     { o2[0] = one; o2[1] = one; o2[2] = bf16bits(nh); o2[3] = bf16bits(nl); }
    }
    *(bhalf8*)(dst + ((size_t)(rb * 3 + 0) * 64 + lane) * 8) = o0;
    *(bhalf8*)(dst + ((size_t)(rb * 3 + 1) * 64 + lane) * 8) = o1;
    *(bhalf8*)(dst + ((size_t)(rb * 3 + 2) * 64 + lane) * 8) = o2;
}

// ---------------- tile kernel: 128x128 per block-iter, 16 mt-tiles per block ----------------
// grid (mc=4, nt=64, b=4) = 1024 blocks. A-frags persistent; row-min accumulated in registers
// across the mt loop; col partials via double-buffered LDS, one sync per iter.
__global__ __launch_bounds__(256, 2) void chamfer_tile(
        const unsigned short* __restrict__ Ap, const unsigned short* __restrict__ Bp,
        float* __restrict__ rowpart, float* __restrict__ colpart) {
    const int mc = blockIdx.x;   // 0..3 : 16-tile mt chunk
    const int nt = blockIdx.y;   // 0..63
    const int b  = blockIdx.z;   // 0..3
    const int tid = threadIdx.x;
    const int wave = tid >> 6, lane = tid & 63;
    const int wr = wave >> 1, wc = wave & 1;
    const int q = lane >> 4, c = lane & 15;

    // A fragments: rows nt*128 + wr*64 + i*16 + c, all 3 k-steps. Loaded once.
    const int rbA0 = b * 512 + nt * 8 + wr * 4;
    bhalf8 af[4][3];
    #pragma unroll
    for (int i = 0; i < 4; i++)
        #pragma unroll
        for (int ks = 0; ks < 3; ks++)
            af[i][ks] = *(const bhalf8*)(Ap + ((size_t)((rbA0 + i) * 3 + ks) * 64 + lane) * 8);

    f32x4 rv[4];                                    // running row-min of d, rows i*16+q*4+r
    #pragma unroll
    for (int i = 0; i < 4; i++) rv[i] = (f32x4){3.0e38f, 3.0e38f, 3.0e38f, 3.0e38f};

    __shared__ __align__(16) float colbuf[2][8][132];  // dbuf: [parity][row-owner wr*4+q][col]
    __shared__ __align__(16) float rowbuf[32][132];    // [col-owner wc*16+c][block row]

    const f32x4 zero4 = {0.f, 0.f, 0.f, 0.f};

    for (int it = 0; it < 16; ++it) {
        const int mt = mc * 16 + it;
        const int rbB0 = b * 512 + mt * 8 + wc * 4;
        bhalf8 bf[4][3];
        #pragma unroll
        for (int j = 0; j < 4; j++)
            #pragma unroll
            for (int ks = 0; ks < 3; ks++)
                bf[j][ks] = *(const bhalf8*)(Bp + ((size_t)((rbB0 + j) * 3 + ks) * 64 + lane) * 8);

        f32x4 acc[4][4];
        #pragma unroll
        for (int i = 0; i < 4; i++)
            #pragma unroll
            for (int j = 0; j < 4; j++)
                acc[i][j] = __builtin_amdgcn_mfma_f32_16x16x32_bf16(af[i][0], bf[j][0], zero4, 0, 0, 0);
        #pragma unroll
        for (int ks = 1; ks < 3; ks++)
            #pragma unroll
            for (int i = 0; i < 4; i++)
                #pragma unroll
                for (int j = 0; j < 4; j++)
                    acc[i][j] = __builtin_amdgcn_mfma_f32_16x16x32_bf16(af[i][ks], bf[j][ks], acc[i][j], 0, 0, 0);
        // acc[i][j][r] = d(row n0+i*16+q*4+r, col m0+j*16+c)  -- full squared distance

        // row-min update (no adds needed; norms are inside d)
        #pragma unroll
        for (int i = 0; i < 4; i++)
            #pragma unroll
            for (int r = 0; r < 4; r++) {
                float t = fminf(fminf(acc[i][0][r], acc[i][1][r]),
                                fminf(acc[i][2][r], acc[i][3][r]));
                rv[i][r] = fminf(rv[i][r], t);
            }

        // col partial: per j, min over this lane's 16 rows
        const int p = it & 1;
        #pragma unroll
        for (int j = 0; j < 4; j++) {
            float v0 = fminf(fminf(acc[0][j][0], acc[0][j][1]), fminf(acc[0][j][2], acc[0][j][3]));
            float v1 = fminf(fminf(acc[1][j][0], acc[1][j][1]), fminf(acc[1][j][2], acc[1][j][3]));
            float v2 = fminf(fminf(acc[2][j][0], acc[2][j][1]), fminf(acc[2][j][2], acc[2][j][3]));
            float v3 = fminf(fminf(acc[3][j][0], acc[3][j][1]), fminf(acc[3][j][2], acc[3][j][3]));
            colbuf[p][wr * 4 + q][wc * 64 + j * 16 + c] = fminf(fminf(v0, v1), fminf(v2, v3));
        }
        __syncthreads();
        if (tid < 128) {
            float v = colbuf[p][0][tid];
            #pragma unroll
            for (int k = 1; k < 8; k++) v = fminf(v, colbuf[p][k][tid]);
            colpart[(((size_t)b * MT_ + mt) * NT_ + nt) * 128 + tid] = v;
        }
    }

    // row combine: once per block, over the 32 column-owner lane groups
    #pragma unroll
    for (int i = 0; i < 4; i++)
        *(f32x4*)&rowbuf[wc * 16 + c][wr * 64 + i * 16 + q * 4] = rv[i];
    __syncthreads();
    if (tid < 128) {
        float v = rowbuf[0][tid];
        #pragma unroll 8
        for (int cc = 1; cc < 32; cc++) v = fminf(v, rowbuf[cc][tid]);
        rowpart[(((size_t)b * NT_ + nt) * 4 + mc) * 128 + tid] = v;
    }
}

// ---------------- reduce: final mins + per-block sums (d already includes norms) ----------------
__global__ __launch_bounds__(256) void chamfer_reduce(
        const float* __restrict__ rowpart, const float* __restrict__ colpart,
        float* __restrict__ sums) {
    const int blk = blockIdx.x;            // 0..255 row side (b,nt); 256..511 col side (b,mt)
    const int tid = threadIdx.x;
    float contrib = 0.f;
    __shared__ __align__(16) f32x4 buf[8][32];

    if (blk < 256) {
        const int b = blk >> 6, nt = blk & 63;
        if (tid < 128) {
            const float* rp = rowpart + (((size_t)b * NT_ + nt) * 4) * 128;
            contrib = fminf(fminf(rp[tid], rp[128 + tid]), fminf(rp[256 + tid], rp[384 + tid]));
        }
    } else {
        const int loc = blk - 256, b = loc >> 6, mt = loc & 63;
        const float* cp = colpart + (((size_t)b * MT_ + mt) * NT_) * 128;
        const int g = tid >> 5, s = tid & 31;
        f32x4 m = {3.0e38f, 3.0e38f, 3.0e38f, 3.0e38f};
        #pragma unroll
        for (int itq = 0; itq < 8; itq++) {
            f32x4 v = *(const f32x4*)(cp + (size_t)(itq * 8 + g) * 128 + s * 4);
            m[0] = fminf(m[0], v[0]); m[1] = fminf(m[1], v[1]);
            m[2] = fminf(m[2], v[2]); m[3] = fminf(m[3], v[3]);
        }
        buf[g][s] = m;
    }
    __syncthreads();
    if (blk >= 256 && tid < 32) {
        f32x4 mn = buf[0][tid];
        #pragma unroll
        for (int g2 = 1; g2 < 8; g2++) {
            f32x4 v = buf[g2][tid];
            mn[0] = fminf(mn[0], v[0]); mn[1] = fminf(mn[1], v[1]);
            mn[2] = fminf(mn[2], v[2]); mn[3] = fminf(mn[3], v[3]);
        }
        contrib = (mn[0] + mn[1]) + (mn[2] + mn[3]);
    }
    __shared__ float sb[256];
    sb[tid] = contrib;
    __syncthreads();
    for (int s2 = 128; s2 > 0; s2 >>= 1) {
        if (tid < s2) sb[tid] += sb[tid + s2];
        __syncthreads();
    }
    if (tid == 0) sums[blk] = sb[0];
}

__global__ void chamfer_final(const float* __restrict__ sums, float* __restrict__ out) {
    int tid = threadIdx.x;  // 256 threads
    float v = sums[tid] * (1.0f / ((float)B_ * (float)N_))
            + sums[256 + tid] * (1.0f / ((float)B_ * (float)M_));
    __shared__ float sb[256];
    sb[tid] = v;
    __syncthreads();
    for (int s = 128; s > 0; s >>= 1) {
        if (tid < s) sb[tid] += sb[tid + s];
        __syncthreads();
    }
    if (tid == 0) out[0] = sb[0];
}

extern "C" void kernel_launch(void* const* d_in, const int* in_sizes, int n_in,
                              void* d_out, int out_size, void* d_ws, size_t ws_size,
                              hipStream_t stream) {
    const float* f  = (const float*)d_in[0];
    const float* f2 = (const float*)d_in[1];
    char* ws = (char*)d_ws;
    unsigned short* Ap = (unsigned short*)(ws + OFF_A);
    unsigned short* Bp = (unsigned short*)(ws + OFF_B);
    float* rowpart = (float*)(ws + OFF_RP);
    float* colpart = (float*)(ws + OFF_CP);
    float* sums    = (float*)(ws + OFF_SM);
    float* out     = (float*)d_out;

    // prep: 4096 waves (one per 16-row block) -> 1024 blocks of 256
    chamfer_prep<<<dim3(1024), dim3(256), 0, stream>>>(f, f2, Ap, Bp);

    // main: 1024 blocks, 16 mt-tiles each
    chamfer_tile<<<dim3(4, NT_, B_), dim3(256), 0, stream>>>(Ap, Bp, rowpart, colpart);

    // reduce -> 512 partial sums -> scalar
    chamfer_reduce<<<dim3(512), dim3(256), 0, stream>>>(rowpart, colpart, sums);
    chamfer_final<<<dim3(1), dim3(256), 0, stream>>>(sums, out);
}

// Round 5
// 130.434 us; speedup vs baseline: 1.8125x; 1.0201x over previous
//
#include <hip/hip_runtime.h>
#include <hip/hip_bf16.h>
#include <stdint.h>

// Problem constants (fixed by reference)
#define B_  4
#define N_  8192
#define M_  8192
#define D_  64
#define KP  96    // padded K: 64 data + (norm_hi, norm_lo, 1, 1) + 28 zeros
#define NT_ 64    // N_/128
#define MT_ 64    // M_/128
#define RBN ((B_ * N_) / 16)   // 2048 16-row blocks on A side

typedef __attribute__((ext_vector_type(8))) short bhalf8;   // 8 bf16 (MFMA A/B frag)
typedef __attribute__((ext_vector_type(4))) float f32x4;    // MFMA C/D frag

// ---- workspace layout (bytes) ----
// A'/B': bf16, fragment-chunk order: chunk(rb, ks=0..2, lane=q*16+c) = row (rb*16+c),
//        k = ks*32 + q*8 .. +7; stored at ((rb*3+ks)*64 + lane)*8 elems -> lane-contiguous 1KB loads.
// K extension fuses norms: A' row n = (-2f[n], nh, nl, 1, 1, 0...), B' row m = (f_[m], 1, 1, nh2, nl2, 0...)
//   => A'.B' = -2 f.f_ + ||f||^2 + ||f_||^2 = full squared distance from MFMA alone.
static const size_t OFF_A  = 0;
static const size_t OFF_B  = (size_t)B_ * N_ * KP * 2;                      // 6,291,456
static const size_t OFF_RP = OFF_B + (size_t)B_ * M_ * KP * 2;              // 12,582,912
static const size_t OFF_CP = OFF_RP + (size_t)B_ * NT_ * 4 * 128 * 4;       // 13,107,200
static const size_t OFF_SM = OFF_CP + (size_t)B_ * MT_ * NT_ * 2 * 128 * 4; // 29,884,416

__device__ __forceinline__ short bf16bits(float x) {
    union { __hip_bfloat16 h; unsigned short u; } cv;
    cv.h = __float2bfloat16(x);
    return (short)cv.u;
}

// ---------------- prep: build K=96 fused-norm fragment layout ----------------
__global__ __launch_bounds__(256) void chamfer_prep(
        const float* __restrict__ f, const float* __restrict__ f2,
        unsigned short* __restrict__ Ap, unsigned short* __restrict__ Bp) {
    const int tid = threadIdx.x;
    const int w = blockIdx.x * 4 + (tid >> 6);   // 16-row block id, 0..4095
    const int lane = tid & 63;
    const int q = lane >> 4, c = lane & 15;
    const bool isA = w < RBN;
    const int rb = isA ? w : w - RBN;
    const float* src = isA ? f : f2;
    unsigned short* dst = isA ? Ap : Bp;
    const float scale = isA ? -2.0f : 1.0f;      // fold the -2 into A; exact in bf16

    const float* row = src + ((size_t)rb * 16 + c) * 64;
    f32x4 u0 = *(const f32x4*)(row + q * 8);
    f32x4 u1 = *(const f32x4*)(row + q * 8 + 4);
    f32x4 u2 = *(const f32x4*)(row + 32 + q * 8);
    f32x4 u3 = *(const f32x4*)(row + 32 + q * 8 + 4);

    float ss = 0.f;
    #pragma unroll
    for (int k = 0; k < 4; k++)
        ss += u0[k] * u0[k] + u1[k] * u1[k] + u2[k] * u2[k] + u3[k] * u3[k];
    ss += __shfl_xor(ss, 16, 64);
    ss += __shfl_xor(ss, 32, 64);                // full ||row c||^2 in every lane

    bhalf8 o0, o1;
    #pragma unroll
    for (int k = 0; k < 4; k++) {
        o0[k]     = bf16bits(u0[k] * scale);
        o0[4 + k] = bf16bits(u1[k] * scale);
        o1[k]     = bf16bits(u2[k] * scale);
        o1[4 + k] = bf16bits(u3[k] * scale);
    }
    bhalf8 o2 = {0, 0, 0, 0, 0, 0, 0, 0};        // k=64..95 zeros except q==0 lanes
    if (q == 0) {
        float nh = __bfloat162float(__float2bfloat16(ss));  // hi part, exact in bf16
        float nl = ss - nh;                                  // residual
        const short one = 0x3F80;                            // bf16 1.0
        if (isA) { o2[0] = bf16bits(nh); o2[1] = bf16bits(nl); o2[2] = one; o2[3] = one; }
        else     { o2[0] = one; o2[1] = one; o2[2] = bf16bits(nh); o2[3] = bf16bits(nl); }
    }
    *(bhalf8*)(dst + ((size_t)(rb * 3 + 0) * 64 + lane) * 8) = o0;
    *(bhalf8*)(dst + ((size_t)(rb * 3 + 1) * 64 + lane) * 8) = o1;
    *(bhalf8*)(dst + ((size_t)(rb * 3 + 2) * 64 + lane) * 8) = o2;
}

// ---------------- tile kernel: barrier-free K-loop ----------------
// grid (mc=4, nt=64, b=4). Per block: A-frags persistent, 32 steps of 32 columns
// (16 mt-tiles x 2 j-pairs). Row-min in registers; col-min combined in-wave via
// shfl_xor over q and stored per-(nt,wr) to global. NO __syncthreads in the loop ->
// B-frag double-buffer prefetch stays in flight (fine-grained vmcnt, not vmcnt(0)).
__global__ __launch_bounds__(256, 2) void chamfer_tile(
        const unsigned short* __restrict__ Ap, const unsigned short* __restrict__ Bp,
        float* __restrict__ rowpart, float* __restrict__ colpart) {
    const int mc = blockIdx.x;   // 0..3 : 16-tile mt chunk
    const int nt = blockIdx.y;   // 0..63
    const int b  = blockIdx.z;   // 0..3
    const int tid = threadIdx.x;
    const int wave = tid >> 6, lane = tid & 63;
    const int wr = wave >> 1, wc = wave & 1;
    const int q = lane >> 4, c = lane & 15;

    // A fragments: rows nt*128 + wr*64 + i*16 + c, 3 k-steps. Loaded once.
    const int rbA0 = b * 512 + nt * 8 + wr * 4;
    bhalf8 af[4][3];
    #pragma unroll
    for (int i = 0; i < 4; i++)
        #pragma unroll
        for (int ks = 0; ks < 3; ks++)
            af[i][ks] = *(const bhalf8*)(Ap + ((size_t)((rbA0 + i) * 3 + ks) * 64 + lane) * 8);

    f32x4 rv[4];                 // running row-min, rows i*16+q*4+r (this wave's 64 rows)
    #pragma unroll
    for (int i = 0; i < 4; i++) rv[i] = (f32x4){3.0e38f, 3.0e38f, 3.0e38f, 3.0e38f};

    const f32x4 zero4 = {0.f, 0.f, 0.f, 0.f};

    auto loadB = [&](int s, bhalf8 (&bf)[2][3]) {
        const int mt = mc * 16 + (s >> 1);
        const int rbB = b * 512 + mt * 8 + wc * 4 + (s & 1) * 2;
        #pragma unroll
        for (int jj = 0; jj < 2; jj++)
            #pragma unroll
            for (int ks = 0; ks < 3; ks++)
                bf[jj][ks] = *(const bhalf8*)(Bp + ((size_t)((rbB + jj) * 3 + ks) * 64 + lane) * 8);
    };

    auto process = [&](int s, bhalf8 (&bf)[2][3]) {
        f32x4 acc[4][2];
        #pragma unroll
        for (int i = 0; i < 4; i++)
            #pragma unroll
            for (int jj = 0; jj < 2; jj++)
                acc[i][jj] = __builtin_amdgcn_mfma_f32_16x16x32_bf16(af[i][0], bf[jj][0], zero4, 0, 0, 0);
        #pragma unroll
        for (int ks = 1; ks < 3; ks++)
            #pragma unroll
            for (int i = 0; i < 4; i++)
                #pragma unroll
                for (int jj = 0; jj < 2; jj++)
                    acc[i][jj] = __builtin_amdgcn_mfma_f32_16x16x32_bf16(af[i][ks], bf[jj][ks], acc[i][jj], 0, 0, 0);
        // acc[i][jj][r] = d(row, col) -- full squared distance

        // row-min: fminf(fminf(a,b),prev) -> v_min3
        #pragma unroll
        for (int i = 0; i < 4; i++)
            #pragma unroll
            for (int r = 0; r < 4; r++)
                rv[i][r] = fminf(fminf(acc[i][0][r], acc[i][1][r]), rv[i][r]);

        // col-min: in-lane over 16 rows, then q-combine via shfl, store per (nt,wr)
        const int mt = mc * 16 + (s >> 1);
        #pragma unroll
        for (int jj = 0; jj < 2; jj++) {
            float t0 = fminf(fminf(acc[0][jj][0], acc[0][jj][1]), fminf(acc[0][jj][2], acc[0][jj][3]));
            float t1 = fminf(fminf(acc[1][jj][0], acc[1][jj][1]), fminf(acc[1][jj][2], acc[1][jj][3]));
            float t2 = fminf(fminf(acc[2][jj][0], acc[2][jj][1]), fminf(acc[2][jj][2], acc[2][jj][3]));
            float t3 = fminf(fminf(acc[3][jj][0], acc[3][jj][1]), fminf(acc[3][jj][2], acc[3][jj][3]));
            float t = fminf(fminf(t0, t1), fminf(t2, t3));
            t = fminf(t, __shfl_xor(t, 16, 64));
            t = fminf(t, __shfl_xor(t, 32, 64));   // min over all 64 of this wave's rows
            if (q == 0)
                colpart[((((size_t)b * 64 + mt) * 64 + nt) * 2 + wr) * 128
                        + wc * 64 + (s & 1) * 32 + jj * 16 + c] = t;
        }
    };

    bhalf8 bf0[2][3], bf1[2][3];
    loadB(0, bf0);
    #pragma unroll 1
    for (int s = 0; s < 32; s += 2) {
        loadB(s + 1, bf1);
        process(s, bf0);
        if (s + 2 < 32) loadB(s + 2, bf0);
        process(s + 1, bf1);
    }

    // row combine: once per block (only __syncthreads in the kernel)
    __shared__ __align__(16) float rowbuf[32][132];
    #pragma unroll
    for (int i = 0; i < 4; i++)
        *(f32x4*)&rowbuf[wc * 16 + c][wr * 64 + i * 16 + q * 4] = rv[i];
    __syncthreads();
    if (tid < 128) {
        float v = rowbuf[0][tid];
        #pragma unroll 8
        for (int cc = 1; cc < 32; cc++) v = fminf(v, rowbuf[cc][tid]);
        rowpart[(((size_t)b * NT_ + nt) * 4 + mc) * 128 + tid] = v;
    }
}

// ---------------- reduce: final mins + per-block sums ----------------
__global__ __launch_bounds__(256) void chamfer_reduce(
        const float* __restrict__ rowpart, const float* __restrict__ colpart,
        float* __restrict__ sums) {
    const int blk = blockIdx.x;            // 0..255 row side (b,nt); 256..511 col side (b,mt)
    const int tid = threadIdx.x;
    float contrib = 0.f;
    __shared__ __align__(16) f32x4 buf[8][32];

    if (blk < 256) {
        const int b = blk >> 6, nt = blk & 63;
        if (tid < 128) {
            const float* rp = rowpart + ((size_t)(b * 64 + nt) * 4) * 128;
            contrib = fminf(fminf(rp[tid], rp[128 + tid]), fminf(rp[256 + tid], rp[384 + tid]));
        }
    } else {
        const int loc = blk - 256, b = loc >> 6, mt = loc & 63;
        const float* cp = colpart + (size_t)(b * 64 + mt) * (64 * 2 * 128);
        const int g = tid >> 5, s = tid & 31;
        f32x4 m = {3.0e38f, 3.0e38f, 3.0e38f, 3.0e38f};
        #pragma unroll
        for (int it = 0; it < 16; it++) {              // 128 (nt,wr) entries / 8 row-groups
            f32x4 v = *(const f32x4*)(cp + (size_t)(it * 8 + g) * 128 + s * 4);
            m[0] = fminf(m[0], v[0]); m[1] = fminf(m[1], v[1]);
            m[2] = fminf(m[2], v[2]); m[3] = fminf(m[3], v[3]);
        }
        buf[g][s] = m;
    }
    __syncthreads();
    if (blk >= 256 && tid < 32) {
        f32x4 mn = buf[0][tid];
        #pragma unroll
        for (int g2 = 1; g2 < 8; g2++) {
            f32x4 v = buf[g2][tid];
            mn[0] = fminf(mn[0], v[0]); mn[1] = fminf(mn[1], v[1]);
            mn[2] = fminf(mn[2], v[2]); mn[3] = fminf(mn[3], v[3]);
        }
        contrib = (mn[0] + mn[1]) + (mn[2] + mn[3]);   // sum of 4 cols' mins
    }
    __shared__ float sb[256];
    sb[tid] = contrib;
    __syncthreads();
    for (int s2 = 128; s2 > 0; s2 >>= 1) {
        if (tid < s2) sb[tid] += sb[tid + s2];
        __syncthreads();
    }
    if (tid == 0) sums[blk] = sb[0];
}

__global__ void chamfer_final(const float* __restrict__ sums, float* __restrict__ out) {
    int tid = threadIdx.x;  // 256 threads
    float v = sums[tid] * (1.0f / ((float)B_ * (float)N_))
            + sums[256 + tid] * (1.0f / ((float)B_ * (float)M_));
    __shared__ float sb[256];
    sb[tid] = v;
    __syncthreads();
    for (int s = 128; s > 0; s >>= 1) {
        if (tid < s) sb[tid] += sb[tid + s];
        __syncthreads();
    }
    if (tid == 0) out[0] = sb[0];
}

extern "C" void kernel_launch(void* const* d_in, const int* in_sizes, int n_in,
                              void* d_out, int out_size, void* d_ws, size_t ws_size,
                              hipStream_t stream) {
    const float* f  = (const float*)d_in[0];
    const float* f2 = (const float*)d_in[1];
    char* ws = (char*)d_ws;
    unsigned short* Ap = (unsigned short*)(ws + OFF_A);
    unsigned short* Bp = (unsigned short*)(ws + OFF_B);
    float* rowpart = (float*)(ws + OFF_RP);
    float* colpart = (float*)(ws + OFF_CP);
    float* sums    = (float*)(ws + OFF_SM);
    float* out     = (float*)d_out;

    // prep: 4096 waves (one per 16-row block) -> 1024 blocks of 256
    chamfer_prep<<<dim3(1024), dim3(256), 0, stream>>>(f, f2, Ap, Bp);

    // main: 1024 blocks, barrier-free 32-step loop
    chamfer_tile<<<dim3(4, NT_, B_), dim3(256), 0, stream>>>(Ap, Bp, rowpart, colpart);

    // reduce -> 512 partial sums -> scalar
    chamfer_reduce<<<dim3(512), dim3(256), 0, stream>>>(rowpart, colpart, sums);
    chamfer_final<<<dim3(1), dim3(256), 0, stream>>>(sums, out);
}

// Round 6
// 126.393 us; speedup vs baseline: 1.8705x; 1.0320x over previous
//
#include <hip/hip_runtime.h>
#include <hip/hip_bf16.h>
#include <stdint.h>

// Problem constants (fixed by reference)
#define B_  4
#define N_  8192
#define M_  8192
#define D_  64
#define KP  96    // padded K: 64 data + (norm_hi, norm_lo, 1, 1) + 28 zeros
#define NT_ 64    // N_/128
#define MT_ 64    // M_/128
#define RBN ((B_ * N_) / 16)   // 2048 16-row blocks on A side

typedef __attribute__((ext_vector_type(8))) short bhalf8;   // 8 bf16 (MFMA A/B frag)
typedef __attribute__((ext_vector_type(4))) float f32x4;    // MFMA C/D frag

// ---- workspace layout (bytes) ----
// A'/B': bf16, fragment-chunk order: chunk(rb, ks=0..2, lane=q*16+c) = row (rb*16+c),
//        k = ks*32 + q*8 .. +7; stored at ((rb*3+ks)*64 + lane)*8 elems -> lane-contiguous 1KB loads.
// K extension fuses norms: A' row n = (-2f[n], nh, nl, 1, 1, 0...), B' row m = (f_[m], 1, 1, nh2, nl2, 0...)
//   => A'.B' = full squared distance straight out of MFMA.
// rowpart/colpart hold float BIT PATTERNS as int (signed-int min == float min for our value range).
static const size_t OFF_A  = 0;
static const size_t OFF_B  = (size_t)B_ * N_ * KP * 2;                   // 6,291,456
static const size_t OFF_RP = OFF_B + (size_t)B_ * M_ * KP * 2;           // 12,582,912
static const size_t OFF_CP = OFF_RP + (size_t)B_ * NT_ * 8 * 128 * 4;    // 13,631,488
// end of CP: + 4*64*64*128*4 = 22,020,096

__device__ __forceinline__ short bf16bits(float x) {
    union { __hip_bfloat16 h; unsigned short u; } cv;
    cv.h = __float2bfloat16(x);
    return (short)cv.u;
}

// ---------------- prep: build K=96 fused-norm fragment layout; zero the output accumulator ----------------
__global__ __launch_bounds__(256) void chamfer_prep(
        const float* __restrict__ f, const float* __restrict__ f2,
        unsigned short* __restrict__ Ap, unsigned short* __restrict__ Bp,
        float* __restrict__ out) {
    const int tid = threadIdx.x;
    if (blockIdx.x == 0 && tid == 0) out[0] = 0.f;   // finalize atomicAdds into this
    const int w = blockIdx.x * 4 + (tid >> 6);       // 16-row block id, 0..4095
    const int lane = tid & 63;
    const int q = lane >> 4, c = lane & 15;
    const bool isA = w < RBN;
    const int rb = isA ? w : w - RBN;
    const float* src = isA ? f : f2;
    unsigned short* dst = isA ? Ap : Bp;
    const float scale = isA ? -2.0f : 1.0f;          // fold the -2 into A; exact in bf16

    const float* row = src + ((size_t)rb * 16 + c) * 64;
    f32x4 u0 = *(const f32x4*)(row + q * 8);
    f32x4 u1 = *(const f32x4*)(row + q * 8 + 4);
    f32x4 u2 = *(const f32x4*)(row + 32 + q * 8);
    f32x4 u3 = *(const f32x4*)(row + 32 + q * 8 + 4);

    float ss = 0.f;
    #pragma unroll
    for (int k = 0; k < 4; k++)
        ss += u0[k] * u0[k] + u1[k] * u1[k] + u2[k] * u2[k] + u3[k] * u3[k];
    ss += __shfl_xor(ss, 16, 64);
    ss += __shfl_xor(ss, 32, 64);                    // full ||row c||^2 in every lane

    bhalf8 o0, o1;
    #pragma unroll
    for (int k = 0; k < 4; k++) {
        o0[k]     = bf16bits(u0[k] * scale);
        o0[4 + k] = bf16bits(u1[k] * scale);
        o1[k]     = bf16bits(u2[k] * scale);
        o1[4 + k] = bf16bits(u3[k] * scale);
    }
    bhalf8 o2 = {0, 0, 0, 0, 0, 0, 0, 0};            // k=64..95 zeros except q==0 lanes
    if (q == 0) {
        float nh = __bfloat162float(__float2bfloat16(ss));  // hi part, exact in bf16
        float nl = ss - nh;                                  // residual
        const short one = 0x3F80;                            // bf16 1.0
        if (isA) { o2[0] = bf16bits(nh); o2[1] = bf16bits(nl); o2[2] = one; o2[3] = one; }
        else     { o2[0] = one; o2[1] = one; o2[2] = bf16bits(nh); o2[3] = bf16bits(nl); }
    }
    *(bhalf8*)(dst + ((size_t)(rb * 3 + 0) * 64 + lane) * 8) = o0;
    *(bhalf8*)(dst + ((size_t)(rb * 3 + 1) * 64 + lane) * 8) = o1;
    *(bhalf8*)(dst + ((size_t)(rb * 3 + 2) * 64 + lane) * 8) = o2;
}

// ---------------- tile kernel: wait-free K-loop with LDS atomic-min epilogue ----------------
// grid (mc=8, nt=64, b=4) = 2048 blocks; 8 mt-tiles per block = 16 steps of 32 cols/wave.
// Row-min in registers; col-min via fire-and-forget ds_min_i32 on float bits (no shfl, no
// barrier, no lgkm wait in the loop). B-frags double-buffered; loads stay in flight.
__global__ __launch_bounds__(256, 2) void chamfer_tile(
        const unsigned short* __restrict__ Ap, const unsigned short* __restrict__ Bp,
        int* __restrict__ rowpart, int* __restrict__ colpart) {
    const int mc = blockIdx.x;   // 0..7 : 8-tile mt chunk
    const int nt = blockIdx.y;   // 0..63
    const int b  = blockIdx.z;   // 0..3
    const int tid = threadIdx.x;
    const int wave = tid >> 6, lane = tid & 63;
    const int wr = wave >> 1, wc = wave & 1;
    const int q = lane >> 4, c = lane & 15;

    __shared__ int colmin[8][128];   // per-mt col mins, float bits, signed-int order
    __shared__ int rowmin[128];
    #pragma unroll
    for (int k = 0; k < 4; k++) ((int*)colmin)[k * 256 + tid] = 0x7FFFFFFF;
    if (tid < 128) rowmin[tid] = 0x7FFFFFFF;
    __syncthreads();

    // A fragments: rows nt*128 + wr*64 + i*16 + c, 3 k-steps. Loaded once.
    const int rbA0 = b * 512 + nt * 8 + wr * 4;
    bhalf8 af[4][3];
    #pragma unroll
    for (int i = 0; i < 4; i++)
        #pragma unroll
        for (int ks = 0; ks < 3; ks++)
            af[i][ks] = *(const bhalf8*)(Ap + ((size_t)((rbA0 + i) * 3 + ks) * 64 + lane) * 8);

    f32x4 rv[4];                 // running row-min, rows i*16+q*4+r (this wave's 64 rows)
    #pragma unroll
    for (int i = 0; i < 4; i++) rv[i] = (f32x4){3.0e38f, 3.0e38f, 3.0e38f, 3.0e38f};

    const f32x4 zero4 = {0.f, 0.f, 0.f, 0.f};

    auto loadB = [&](int s, bhalf8 (&bf)[2][3]) {
        const int rbB = b * 512 + (mc * 8 + (s >> 1)) * 8 + wc * 4 + (s & 1) * 2;
        #pragma unroll
        for (int jj = 0; jj < 2; jj++)
            #pragma unroll
            for (int ks = 0; ks < 3; ks++)
                bf[jj][ks] = *(const bhalf8*)(Bp + ((size_t)((rbB + jj) * 3 + ks) * 64 + lane) * 8);
    };

    auto process = [&](int s, bhalf8 (&bf)[2][3]) {
        f32x4 acc[4][2];
        #pragma unroll
        for (int i = 0; i < 4; i++)
            #pragma unroll
            for (int jj = 0; jj < 2; jj++)
                acc[i][jj] = __builtin_amdgcn_mfma_f32_16x16x32_bf16(af[i][0], bf[jj][0], zero4, 0, 0, 0);
        #pragma unroll
        for (int ks = 1; ks < 3; ks++)
            #pragma unroll
            for (int i = 0; i < 4; i++)
                #pragma unroll
                for (int jj = 0; jj < 2; jj++)
                    acc[i][jj] = __builtin_amdgcn_mfma_f32_16x16x32_bf16(af[i][ks], bf[jj][ks], acc[i][jj], 0, 0, 0);
        // acc[i][jj][r] = d(row, col) -- full squared distance

        // row-min: v_min3 per (i,r)
        #pragma unroll
        for (int i = 0; i < 4; i++)
            #pragma unroll
            for (int r = 0; r < 4; r++)
                rv[i][r] = fminf(fminf(acc[i][0][r], acc[i][1][r]), rv[i][r]);

        // col-min partial over this lane's 16 rows -> fire-and-forget LDS atomic (no wait)
        const int mtl = s >> 1;
        #pragma unroll
        for (int jj = 0; jj < 2; jj++) {
            float t0 = fminf(fminf(acc[0][jj][0], acc[0][jj][1]), fminf(acc[0][jj][2], acc[0][jj][3]));
            float t1 = fminf(fminf(acc[1][jj][0], acc[1][jj][1]), fminf(acc[1][jj][2], acc[1][jj][3]));
            float t2 = fminf(fminf(acc[2][jj][0], acc[2][jj][1]), fminf(acc[2][jj][2], acc[2][jj][3]));
            float t3 = fminf(fminf(acc[3][jj][0], acc[3][jj][1]), fminf(acc[3][jj][2], acc[3][jj][3]));
            float t  = fminf(fminf(t0, t1), fminf(t2, t3));
            atomicMin(&colmin[mtl][wc * 64 + (s & 1) * 32 + jj * 16 + c], __float_as_int(t));
        }
    };

    bhalf8 bf0[2][3], bf1[2][3];
    loadB(0, bf0);
    #pragma unroll 1
    for (int s = 0; s < 16; s += 2) {
        loadB(s + 1, bf1);
        process(s, bf0);
        if (s + 2 < 16) loadB(s + 2, bf0);
        process(s + 1, bf1);
    }

    // flush register row-mins to LDS (atomic over the 32 (wc,c) column-owner groups)
    #pragma unroll
    for (int i = 0; i < 4; i++)
        #pragma unroll
        for (int r = 0; r < 4; r++)
            atomicMin(&rowmin[wr * 64 + i * 16 + q * 4 + r], __float_as_int(rv[i][r]));
    __syncthreads();   // only barrier after init: all atomics (lgkm) drained here

    if (tid < 128) {
        rowpart[((size_t)(b * 64 + nt) * 8 + mc) * 128 + tid] = rowmin[tid];
    } else {
        const int t = tid - 128;
        #pragma unroll
        for (int k = 0; k < 8; k++)
            colpart[((size_t)(b * 64 + mc * 8 + k) * 64 + nt) * 128 + t] = colmin[k][t];
    }
}

// ---------------- finalize: global min over partials + mean, single kernel ----------------
__global__ __launch_bounds__(256) void chamfer_finalize(
        const int* __restrict__ rowpart, const int* __restrict__ colpart,
        float* __restrict__ out) {
    const int blk = blockIdx.x;      // 0..255 row side (b,nt); 256..511 col side (b,mt)
    const int tid = threadIdx.x;
    float val = 0.f, scale;
    __shared__ int hbuf[128];

    if (blk < 256) {
        scale = 1.0f / ((float)B_ * (float)N_);
        if (tid < 128) {
            const int* rp = rowpart + (size_t)blk * 8 * 128;
            int m = rp[tid];
            #pragma unroll
            for (int k = 1; k < 8; k++) m = min(m, rp[k * 128 + tid]);
            val = __int_as_float(m);
        }
    } else {
        scale = 1.0f / ((float)B_ * (float)M_);
        const int* cp = colpart + (size_t)(blk - 256) * 64 * 128;
        const int t = tid & 127, h = tid >> 7;
        int m = 0x7FFFFFFF;
        for (int ntb = h * 32; ntb < h * 32 + 32; ntb++)
            m = min(m, cp[(size_t)ntb * 128 + t]);
        if (h == 1) hbuf[t] = m;
        __syncthreads();
        if (h == 0) val = __int_as_float(min(m, hbuf[t]));
    }

    __shared__ float sb[256];
    sb[tid] = val * scale;
    __syncthreads();
    for (int s = 128; s > 0; s >>= 1) {
        if (tid < s) sb[tid] += sb[tid + s];
        __syncthreads();
    }
    if (tid == 0) atomicAdd(out, sb[0]);
}

extern "C" void kernel_launch(void* const* d_in, const int* in_sizes, int n_in,
                              void* d_out, int out_size, void* d_ws, size_t ws_size,
                              hipStream_t stream) {
    const float* f  = (const float*)d_in[0];
    const float* f2 = (const float*)d_in[1];
    char* ws = (char*)d_ws;
    unsigned short* Ap = (unsigned short*)(ws + OFF_A);
    unsigned short* Bp = (unsigned short*)(ws + OFF_B);
    int* rowpart = (int*)(ws + OFF_RP);
    int* colpart = (int*)(ws + OFF_CP);
    float* out   = (float*)d_out;

    // prep: 4096 waves (one per 16-row block) -> 1024 blocks; also zeroes out[0]
    chamfer_prep<<<dim3(1024), dim3(256), 0, stream>>>(f, f2, Ap, Bp, out);

    // main: 2048 blocks, wait-free 16-step loop
    chamfer_tile<<<dim3(8, NT_, B_), dim3(256), 0, stream>>>(Ap, Bp, rowpart, colpart);

    // finalize: mins + means + atomicAdd into out
    chamfer_finalize<<<dim3(512), dim3(256), 0, stream>>>(rowpart, colpart, out);
}